// Round 5
// baseline (747.437 us; speedup 1.0000x reference)
//
#include <hip/hip_runtime.h>

// ThreeStateExplorer: B=256 particles, T=100k steps.
//   k[t]   = inclusive cumsum(states==2)
//   vel[t] = (states[t]==2 ? 0 : e0s[b,k[t]] * (states[t]==0 ? sp0 : sp1))
//   X[t]   = x0 + DT * cumsum(vel)
//
// R7: bench time decomposes as ~395 us fixed harness fills + kernel. Kernel was
// 216 us (R5 profile): VALUBusy 19%, HBM 24%, occupancy 45% => latency-PHASE
// bound, ~40k cycles per chunk vs ~7k of issue. Lever: fewer, fatter chunks.
// IPT 8->16 (13 -> 7 chunks). LDS window staging reverted (R5: FETCH dropped to
// 100 MB but kernel got slower — L2/L3 already absorbed gather redundancy).
// Structure = verified R2 chunk-scan: direct gathers, 2 barriers/chunk,
// next-chunk states prefetch, contiguous float4 stores.

#define NT    1024          // threads per block (16 waves)
#define IPT   16            // elements per thread per chunk (was 8)
#define CHUNK (NT * IPT)    // 16384
#define NW    (NT / 64)     // 16 waves

__device__ __forceinline__ void load_states(const int* __restrict__ st, int lim,
                                            int e0i, int out[IPT]) {
    if (e0i + IPT <= lim) {
        int4 a = *(const int4*)(st + e0i);
        int4 b = *(const int4*)(st + e0i + 4);
        int4 c = *(const int4*)(st + e0i + 8);
        int4 d = *(const int4*)(st + e0i + 12);
        out[0]  = a.x; out[1]  = a.y; out[2]  = a.z; out[3]  = a.w;
        out[4]  = b.x; out[5]  = b.y; out[6]  = b.z; out[7]  = b.w;
        out[8]  = c.x; out[9]  = c.y; out[10] = c.z; out[11] = c.w;
        out[12] = d.x; out[13] = d.y; out[14] = d.z; out[15] = d.w;
    } else {
        #pragma unroll
        for (int j = 0; j < IPT; ++j)
            out[j] = (e0i + j < lim) ? st[e0i + j] : 3;  // sentinel: vel=0, no tumble
    }
}

__global__ __launch_bounds__(NT)
void traj_kernel(const int*   __restrict__ states,   // (B,T)
                 const float* __restrict__ e0s,      // (B,T+1,3)
                 const float* __restrict__ sp0v,     // (B,)
                 const float* __restrict__ sp1v,     // (B,)
                 const float* __restrict__ x0,       // (B,3)
                 float*       __restrict__ X,        // (B,T,3)
                 int T)
{
    const int b    = blockIdx.x;
    const int tid  = threadIdx.x;
    const int lane = tid & 63;
    const int wid  = tid >> 6;

    __shared__ int   s_wi[NW];
    __shared__ float s_wf[NW][3];

    const int*   st = states + (size_t)b * T;
    const float* er = e0s    + (size_t)b * (T + 1) * 3;
    float*       xr = X      + (size_t)b * T * 3;
    const float sp0 = sp0v[b], sp1 = sp1v[b];
    const float x00 = x0[3 * b + 0], x01 = x0[3 * b + 1], x02 = x0[3 * b + 2];

    int   kc  = 0;                          // tumble-count carry
    float pcx = 0.f, pcy = 0.f, pcz = 0.f;  // position carry (un-scaled vel sum)

    int cur[IPT];
    load_states(st, T, tid * IPT, cur);

    for (int base = 0; base < T; base += CHUNK) {
        // ---- prefetch next chunk's states (in flight under this chunk's work)
        int nxt[IPT];
        const bool has_next = (base + CHUNK) < T;   // wave-uniform
        if (has_next) load_states(st, T, base + CHUNK + tid * IPT, nxt);

        // ---- tumble-count block scan
        int c = 0;
        #pragma unroll
        for (int j = 0; j < IPT; ++j) c += (cur[j] == 2);
        int incl = c;
        #pragma unroll
        for (int d = 1; d < 64; d <<= 1) {
            int n = __shfl_up(incl, d, 64);
            if (lane >= d) incl += n;
        }
        if (lane == 63) s_wi[wid] = incl;
        __syncthreads();                                   // barrier 1
        int wex = 0, btot = 0;
        #pragma unroll
        for (int w = 0; w < NW; ++w) {
            int t = s_wi[w];
            wex  += (w < wid) ? t : 0;
            btot += t;
        }
        int k = kc + wex + (incl - c);    // tumbles strictly before my 1st elem

        // ---- batched direct gathers (addresses known; loads issue together,
        //      L2/L3 absorbs the intra-block window reuse — measured R5)
        float ex[IPT], ey[IPT], ez[IPT];
        #pragma unroll
        for (int j = 0; j < IPT; ++j) {
            const int s = cur[j];
            k += (s == 2);                // inclusive count; sp=0 at tumble
            const float sp = (s == 0) ? sp0 : ((s == 1) ? sp1 : 0.f);
            const float* e = er + (size_t)k * 3;   // k <= T: always in bounds
            ex[j] = e[0] * sp;
            ey[j] = e[1] * sp;
            ez[j] = e[2] * sp;
        }

        // ---- thread-local inclusive prefix, in place
        float px = 0.f, py = 0.f, pz = 0.f;
        #pragma unroll
        for (int j = 0; j < IPT; ++j) {
            px += ex[j]; ex[j] = px;
            py += ey[j]; ey[j] = py;
            pz += ez[j]; ez[j] = pz;
        }

        // ---- block scan (float3) of thread totals
        float ix = px, iy = py, iz = pz;
        #pragma unroll
        for (int d = 1; d < 64; d <<= 1) {
            float nx = __shfl_up(ix, d, 64);
            float ny = __shfl_up(iy, d, 64);
            float nz = __shfl_up(iz, d, 64);
            if (lane >= d) { ix += nx; iy += ny; iz += nz; }
        }
        if (lane == 63) { s_wf[wid][0] = ix; s_wf[wid][1] = iy; s_wf[wid][2] = iz; }
        __syncthreads();                                   // barrier 2
        float wfx = 0.f, wfy = 0.f, wfz = 0.f, btx = 0.f, bty = 0.f, btz = 0.f;
        #pragma unroll
        for (int w = 0; w < NW; ++w) {
            float tx = s_wf[w][0], ty = s_wf[w][1], tz = s_wf[w][2];
            if (w < wid) { wfx += tx; wfy += ty; wfz += tz; }
            btx += tx; bty += ty; btz += tz;
        }
        const float bx = pcx + wfx + (ix - px);
        const float by = pcy + wfy + (iy - py);
        const float bz = pcz + wfz + (iz - pz);

        // ---- finalize + store (192 B contiguous/thread, 12 x float4)
        #define FX(j) (x00 + (bx + ex[j]) * 0.1f)
        #define FY(j) (x01 + (by + ey[j]) * 0.1f)
        #define FZ(j) (x02 + (bz + ez[j]) * 0.1f)
        const int e0i = base + tid * IPT;
        if (e0i + IPT <= T) {
            float4* d4 = (float4*)(xr + (size_t)e0i * 3);  // 192 B offset: 16B-aligned
            #define PACK3(m, j0, j1, j2, j3)                                      \
                d4[m]     = make_float4(FX(j0), FY(j0), FZ(j0), FX(j1));          \
                d4[m + 1] = make_float4(FY(j1), FZ(j1), FX(j2), FY(j2));          \
                d4[m + 2] = make_float4(FZ(j2), FX(j3), FY(j3), FZ(j3));
            PACK3(0,  0,  1,  2,  3)
            PACK3(3,  4,  5,  6,  7)
            PACK3(6,  8,  9, 10, 11)
            PACK3(9, 12, 13, 14, 15)
            #undef PACK3
        } else {
            #pragma unroll
            for (int j = 0; j < IPT; ++j)
                if (e0i + j < T) {
                    float* d = xr + (size_t)(e0i + j) * 3;
                    d[0] = FX(j); d[1] = FY(j); d[2] = FZ(j);
                }
        }
        #undef FX
        #undef FY
        #undef FZ

        // ---- carries (uniform; hazards: s_wi next write after this B2, s_wf
        //      next write after next B1)
        kc  += btot;
        pcx += btx; pcy += bty; pcz += btz;

        #pragma unroll
        for (int j = 0; j < IPT; ++j) cur[j] = nxt[j];
    }
}

extern "C" void kernel_launch(void* const* d_in, const int* in_sizes, int n_in,
                              void* d_out, int out_size, void* d_ws, size_t ws_size,
                              hipStream_t stream) {
    const int*   states = (const int*)  d_in[0];
    const float* e0s    = (const float*)d_in[1];
    const float* sp0    = (const float*)d_in[2];
    const float* sp1    = (const float*)d_in[3];
    const float* x0     = (const float*)d_in[4];
    float*       X      = (float*)d_out;

    const int B = in_sizes[2];            // speed_0 has one entry per particle
    const int T = in_sizes[0] / B;        // states is (B,T)

    traj_kernel<<<dim3(B), dim3(NT), 0, stream>>>(states, e0s, sp0, sp1, x0, X, T);
}

// Round 7
// 558.527 us; speedup vs baseline: 1.3382x; 1.3382x over previous
//
#include <hip/hip_runtime.h>

// ThreeStateExplorer: B=256 particles, T=100k steps.
//   k[t]   = inclusive cumsum(states==2)
//   vel[t] = (states[t]==2 ? 0 : e0s[b,k[t]] * (states[t]==0 ? sp0 : sp1))
//   X[t]   = x0 + DT * cumsum(vel)
//
// R9: store-coalescing via wave-local LDS transpose, mapping FIXED vs R8.
// R8's two-half scheme was wrong: the staged set {f4 : f%6 < 3} is not a
// contiguous output range. Now each wave has a FULL 6KB slice (384 float4;
// 16 waves = 96KB LDS, fits 160KB at our 1 block/CU): lane writes its 6 f4s
// at wslice[lane*6+m], then the wave stores wslice[m*64+lane] -> 6x 1KB
// fully-contiguous global stores (full cache lines; harness memset sustains
// 6.4 TB/s on this same buffer). Motivation: R7 proved the strided store
// pattern is the component that misbehaves (3x WRITE amplification at IPT=16);
// R3/R4/R5 exonerated barriers/occupancy/gather-staging.
// Wave-local => no new barriers (per-wave DS ordering). IPT=8, direct gathers.

#define NT    1024          // threads per block (16 waves)
#define IPT   8             // elements per thread per chunk
#define CHUNK (NT * IPT)    // 8192
#define NW    (NT / 64)     // 16 waves

__device__ __forceinline__ void load_states(const int* __restrict__ st, int lim,
                                            int e0i, int out[IPT]) {
    if (e0i + IPT <= lim) {
        int4 a = *(const int4*)(st + e0i);
        int4 b = *(const int4*)(st + e0i + 4);
        out[0] = a.x; out[1] = a.y; out[2] = a.z; out[3] = a.w;
        out[4] = b.x; out[5] = b.y; out[6] = b.z; out[7] = b.w;
    } else {
        #pragma unroll
        for (int j = 0; j < IPT; ++j)
            out[j] = (e0i + j < lim) ? st[e0i + j] : 3;  // sentinel: vel=0, no tumble
    }
}

__global__ __launch_bounds__(NT)
void traj_kernel(const int*   __restrict__ states,   // (B,T)
                 const float* __restrict__ e0s,      // (B,T+1,3)
                 const float* __restrict__ sp0v,     // (B,)
                 const float* __restrict__ sp1v,     // (B,)
                 const float* __restrict__ x0,       // (B,3)
                 float*       __restrict__ X,        // (B,T,3)
                 int T)
{
    const int b    = blockIdx.x;
    const int tid  = threadIdx.x;
    const int lane = tid & 63;
    const int wid  = tid >> 6;

    __shared__ float4 s_t[NW * 384];    // 96 KB: one 6KB transpose slice per wave
    __shared__ int    s_wi[NW];
    __shared__ float  s_wf[NW][3];

    const int*   st = states + (size_t)b * T;
    const float* er = e0s    + (size_t)b * (T + 1) * 3;
    float*       xr = X      + (size_t)b * T * 3;
    const float sp0 = sp0v[b], sp1 = sp1v[b];
    const float x00 = x0[3 * b + 0], x01 = x0[3 * b + 1], x02 = x0[3 * b + 2];

    int   kc  = 0;                          // tumble-count carry
    float pcx = 0.f, pcy = 0.f, pcz = 0.f;  // position carry (un-scaled vel sum)

    int cur[IPT];
    load_states(st, T, tid * IPT, cur);

    for (int base = 0; base < T; base += CHUNK) {
        // ---- prefetch next chunk's states (in flight under this chunk's work)
        int nxt[IPT];
        const bool has_next = (base + CHUNK) < T;   // wave-uniform
        if (has_next) load_states(st, T, base + CHUNK + tid * IPT, nxt);

        // ---- tumble-count block scan
        int c = 0;
        #pragma unroll
        for (int j = 0; j < IPT; ++j) c += (cur[j] == 2);
        int incl = c;
        #pragma unroll
        for (int d = 1; d < 64; d <<= 1) {
            int n = __shfl_up(incl, d, 64);
            if (lane >= d) incl += n;
        }
        if (lane == 63) s_wi[wid] = incl;
        __syncthreads();                                   // barrier 1
        int wex = 0, btot = 0;
        #pragma unroll
        for (int w = 0; w < NW; ++w) {
            int t = s_wi[w];
            wex  += (w < wid) ? t : 0;
            btot += t;
        }
        int k = kc + wex + (incl - c);    // tumbles strictly before my 1st elem

        // ---- batched direct gathers (L2/L3 absorbs window reuse — R5 measured)
        float ex[IPT], ey[IPT], ez[IPT];
        #pragma unroll
        for (int j = 0; j < IPT; ++j) {
            const int s = cur[j];
            k += (s == 2);                // inclusive count; sp=0 at tumble
            const float sp = (s == 0) ? sp0 : ((s == 1) ? sp1 : 0.f);
            const float* e = er + (size_t)k * 3;   // k <= T: always in bounds
            ex[j] = e[0] * sp;
            ey[j] = e[1] * sp;
            ez[j] = e[2] * sp;
        }

        // ---- thread-local inclusive prefix, in place
        float px = 0.f, py = 0.f, pz = 0.f;
        #pragma unroll
        for (int j = 0; j < IPT; ++j) {
            px += ex[j]; ex[j] = px;
            py += ey[j]; ey[j] = py;
            pz += ez[j]; ez[j] = pz;
        }

        // ---- block scan (float3) of thread totals
        float ix = px, iy = py, iz = pz;
        #pragma unroll
        for (int d = 1; d < 64; d <<= 1) {
            float nx = __shfl_up(ix, d, 64);
            float ny = __shfl_up(iy, d, 64);
            float nz = __shfl_up(iz, d, 64);
            if (lane >= d) { ix += nx; iy += ny; iz += nz; }
        }
        if (lane == 63) { s_wf[wid][0] = ix; s_wf[wid][1] = iy; s_wf[wid][2] = iz; }
        __syncthreads();                                   // barrier 2
        float wfx = 0.f, wfy = 0.f, wfz = 0.f, btx = 0.f, bty = 0.f, btz = 0.f;
        #pragma unroll
        for (int w = 0; w < NW; ++w) {
            float tx = s_wf[w][0], ty = s_wf[w][1], tz = s_wf[w][2];
            if (w < wid) { wfx += tx; wfy += ty; wfz += tz; }
            btx += tx; bty += ty; btz += tz;
        }
        const float bx = pcx + wfx + (ix - px);
        const float by = pcy + wfy + (iy - py);
        const float bz = pcz + wfz + (iz - pz);

        // ---- finalize + store
        #define FX(j) (x00 + (bx + ex[j]) * 0.1f)
        #define FY(j) (x01 + (by + ey[j]) * 0.1f)
        #define FZ(j) (x02 + (bz + ez[j]) * 0.1f)
        if (base + CHUNK <= T) {
            // Wave-local transpose through this wave's 6KB slice.
            // Logical f4 index within the wave region: f = lane*6+m (producer)
            // = m_r*64+lane_r (consumer). phys = f (identity). Producer stride
            // 6 f4 covers 4/8 bank-sets (~2x on writes, ~6us total — accepted);
            // consumer stride 1 is bank-optimal. Per-wave DS ordering makes the
            // write->read dependence safe without a barrier; slice is private
            // to this wave so there is no cross-wave or cross-chunk hazard.
            float4* wslice = s_t + wid * 384;
            float4* gbase  = (float4*)(xr + (size_t)base * 3) + (size_t)wid * 384;

            wslice[lane * 6 + 0] = make_float4(FX(0), FY(0), FZ(0), FX(1));
            wslice[lane * 6 + 1] = make_float4(FY(1), FZ(1), FX(2), FY(2));
            wslice[lane * 6 + 2] = make_float4(FZ(2), FX(3), FY(3), FZ(3));
            wslice[lane * 6 + 3] = make_float4(FX(4), FY(4), FZ(4), FX(5));
            wslice[lane * 6 + 4] = make_float4(FY(5), FZ(5), FX(6), FY(6));
            wslice[lane * 6 + 5] = make_float4(FZ(6), FX(7), FY(7), FZ(7));
            #pragma unroll
            for (int m = 0; m < 6; ++m)
                gbase[m * 64 + lane] = wslice[m * 64 + lane];  // 1KB contiguous/instr
        } else {
            const int e0i = base + tid * IPT;
            #pragma unroll
            for (int j = 0; j < IPT; ++j)
                if (e0i + j < T) {
                    float* d = xr + (size_t)(e0i + j) * 3;
                    d[0] = FX(j); d[1] = FY(j); d[2] = FZ(j);
                }
        }
        #undef FX
        #undef FY
        #undef FZ

        // ---- carries (uniform; s_wi next write after this B2, s_wf next write
        //      after next B1; s_t is wave-private — no cross-wave hazard)
        kc  += btot;
        pcx += btx; pcy += bty; pcz += btz;

        #pragma unroll
        for (int j = 0; j < IPT; ++j) cur[j] = nxt[j];
    }
}

extern "C" void kernel_launch(void* const* d_in, const int* in_sizes, int n_in,
                              void* d_out, int out_size, void* d_ws, size_t ws_size,
                              hipStream_t stream) {
    const int*   states = (const int*)  d_in[0];
    const float* e0s    = (const float*)d_in[1];
    const float* sp0    = (const float*)d_in[2];
    const float* sp1    = (const float*)d_in[3];
    const float* x0     = (const float*)d_in[4];
    float*       X      = (float*)d_out;

    const int B = in_sizes[2];            // speed_0 has one entry per particle
    const int T = in_sizes[0] / B;        // states is (B,T)

    traj_kernel<<<dim3(B), dim3(NT), 0, stream>>>(states, e0s, sp0, sp1, x0, X, T);
}